// Round 13
// baseline (324.927 us; speedup 1.0000x reference)
//
#include <hip/hip_runtime.h>
#include <hip/hip_bf16.h>
#include <cstdint>

// SNN: Poisson encode (noise < x) -> [T=32] { h = sp@W1^T; v+=h; spike=(v>1); v-=spike; logits += spike@W2^T }
// B=8192, T=32, D_IN=784 (pad K to 800 = 25x32), D_H=100 (pad N to 128), D_OUT=10.
//
// v13: v12 algorithm, reshaped for 4 blocks/CU phase overlap.
//   Grid 2048 = 16 t-pairs x 128 btiles; 256 thr (4 waves, 2M x 2N); block =
//   64 b-rows x 128 h x 2 t. acc 64 VGPR; launch_bounds(256,4) caps VGPR at 128
//   -> 4 waves/SIMD -> 4 independent blocks/CU (v12 had 2) so pack (HBM-stream)
//   and GEMM (MFMA/VALU) phases overlap across blocks.
//   Pack: 49 passes; per pass load x f4 once + noise[t0],[t1] f4 (nontemporal),
//   ballot-pack both into sB[2][64*50] (v7 bit mapping, verified).
//   GEMM: per kt: expand pk for both mt (verified expander), per nt load wf
//   fragment, 8 MFMA. H [b][t][100] nontemporal stores. snn_scan unchanged.

typedef __attribute__((ext_vector_type(8))) short bf16x8;
typedef __attribute__((ext_vector_type(4))) float f32x4;

#define D_IN 784
#define NB 8192
#define KT 25   // K tiles of 32 (800 padded)
#define DH 100

// ---------------- K0: pack W1 into fragment-ready bf16 hi/lo ----------------
// Fragment f = (kt*8 + nt), stored as [f][hi(512 ushorts) | lo(512 ushorts)].
// B-slot(lane l, elem j): n = nt*16 + (l&15), i = kt*32 + (l>>4)*8 + j.
__global__ void prep_w1(const float* __restrict__ W1, unsigned short* __restrict__ wf) {
    int idx = blockIdx.x * 256 + threadIdx.x;           // 25*8*64 = 12800
    if (idx >= KT * 8 * 64) return;
    int l  = idx & 63;
    int nt = (idx >> 6) & 7;
    int kt = idx >> 9;
    int n  = nt * 16 + (l & 15);
    int i0 = kt * 32 + (l >> 4) * 8;
    size_t fbase = (size_t)(kt * 8 + nt) * 1024;
    #pragma unroll
    for (int j = 0; j < 8; ++j) {
        int i = i0 + j;
        float w = (n < DH && i < D_IN) ? W1[n * D_IN + i] : 0.f;
        uint32_t ub = __float_as_uint(w);
        uint32_t rh = ub + 0x7FFFu + ((ub >> 16) & 1u);
        unsigned short h = (unsigned short)(rh >> 16);
        float hf = __uint_as_float(((uint32_t)h) << 16);
        float resid = w - hf;
        uint32_t ul = __float_as_uint(resid);
        uint32_t rl = ul + 0x7FFFu + ((ul >> 16) & 1u);
        unsigned short lo = (unsigned short)(rl >> 16);
        wf[fbase + l * 8 + j]       = h;
        wf[fbase + 512 + l * 8 + j] = lo;
    }
}

__device__ __forceinline__ f32x4 ldnt(const float* p) {
    return __builtin_nontemporal_load(reinterpret_cast<const f32x4*>(p));
}
__device__ __forceinline__ f32x4 ld(const float* p) {
    return *reinterpret_cast<const f32x4*>(p);
}

// ---------------- K1: t-pair pack+GEMM (64-row blocks) ----------------
// Pack mapping (verified): pass p, thread owns f4-slot s = p*256+tid (49x256 =
// 12544 = 64x196 exact); ushort-group g = p*64 + wave*16 + u, row = g/49,
// colu = g%49; stored bit q <-> float offset f in group: q = 4*(f&3)+(f>>2).
// Expand (verified): lg=lane>>4, qe0=(lg&1)*2+(lg>>1)*16; dword d:
// qe = qe0 + (d&1)*8 + (d>>1); bits {qe, qe+4}.
__global__ __launch_bounds__(256, 4) void snn_gemm2(const float* __restrict__ x,
                                                    const float* __restrict__ noise,
                                                    const unsigned short* __restrict__ wf,
                                                    float* __restrict__ H) {
    __shared__ __align__(4) unsigned short sB[2][64 * 50];   // 2 x 6.4KB
    const int tid  = threadIdx.x;
    const int lane = tid & 63;
    const int wave = tid >> 6;
    const int L     = blockIdx.x;
    const int btile = (L & 7) * 16 + ((L >> 3) & 15);  // XCD swizzle: x slice 3.2MB/XCD
    const int tp    = L >> 7;                           // t-pair 0..15
    const int b0    = btile * 64;
    const int u     = lane & 15;
    const int lg    = lane >> 4;
    const int Mhalf = wave >> 1;       // 0..1 (32 rows each)
    const int Nq    = wave & 1;        // 0..1 (ntiles Nq*4 .. +3)

    if (tid < 128) sB[tid >> 6][(tid & 63) * 50 + 49] = 0;   // k-pad both tiles

    const float* xb  = x + (size_t)b0 * D_IN;
    const float* nb0 = noise + (size_t)(2 * tp) * ((size_t)NB * D_IN) + (size_t)b0 * D_IN;
    const float* nb1 = nb0 + (size_t)NB * D_IN;

    // ---- pack phase: 49 passes, x loaded once per pass ----
    {
        f32x4 xA, n0A, n1A;
        {
            const size_t fo = (size_t)tid * 4;
            xA  = ld(xb + fo);
            n0A = ldnt(nb0 + fo);
            n1A = ldnt(nb1 + fo);
        }
        #pragma unroll 2
        for (int p = 0; p < 49; ++p) {
            const f32x4 xC = xA, n0C = n0A, n1C = n1A;
            if (p < 48) {
                const size_t fo = (size_t)(p + 1) * 1024 + (size_t)tid * 4;
                xA  = ld(xb + fo);
                n0A = ldnt(nb0 + fo);
                n1A = ldnt(nb1 + fo);
            }
            const unsigned long long a0 = __ballot(n0C[0] < xC[0]);
            const unsigned long long a1 = __ballot(n0C[1] < xC[1]);
            const unsigned long long a2 = __ballot(n0C[2] < xC[2]);
            const unsigned long long a3 = __ballot(n0C[3] < xC[3]);
            const unsigned long long c0 = __ballot(n1C[0] < xC[0]);
            const unsigned long long c1 = __ballot(n1C[1] < xC[1]);
            const unsigned long long c2 = __ballot(n1C[2] < xC[2]);
            const unsigned long long c3 = __ballot(n1C[3] < xC[3]);
            if (lane < 16) {
                const int g = p * 64 + wave * 16 + u;             // < 3136
                const uint32_t row = ((uint32_t)g * 42800u) >> 21; // g/49 exact
                const int off = (int)row * 50 + (g - (int)row * 49);
                const uint32_t v0 = (uint32_t)((a0 >> (4 * u)) & 15ull)
                                  | ((uint32_t)((a1 >> (4 * u)) & 15ull) << 4)
                                  | ((uint32_t)((a2 >> (4 * u)) & 15ull) << 8)
                                  | ((uint32_t)((a3 >> (4 * u)) & 15ull) << 12);
                const uint32_t v1 = (uint32_t)((c0 >> (4 * u)) & 15ull)
                                  | ((uint32_t)((c1 >> (4 * u)) & 15ull) << 4)
                                  | ((uint32_t)((c2 >> (4 * u)) & 15ull) << 8)
                                  | ((uint32_t)((c3 >> (4 * u)) & 15ull) << 12);
                sB[0][off] = (unsigned short)v0;
                sB[1][off] = (unsigned short)v1;
            }
        }
    }
    __syncthreads();

    // ---- GEMM phase ----
    const uint32_t* s0 = reinterpret_cast<const uint32_t*>(&sB[0][0]);
    const uint32_t* s1 = reinterpret_cast<const uint32_t*>(&sB[1][0]);
    const int qe0 = (lg & 1) * 2 + (lg >> 1) * 16;

    f32x4 acc[2][2][4];   // [t][mt][nt]
    #pragma unroll
    for (int tt = 0; tt < 2; ++tt)
        #pragma unroll
        for (int mt = 0; mt < 2; ++mt)
            #pragma unroll
            for (int nt = 0; nt < 4; ++nt) acc[tt][mt][nt] = (f32x4){0, 0, 0, 0};

    #pragma unroll 2
    for (int kt = 0; kt < KT; ++kt) {
        // expand A-fragments for both mt, both t (16 dwords live)
        union { uint32_t uu[4]; bf16x8 vv; } pk[2][2];   // [t][mt]
        #pragma unroll
        for (int mt = 0; mt < 2; ++mt) {
            const int ro = (Mhalf * 32 + mt * 16 + u) * 25 + kt;
            const uint32_t g0 = s0[ro];
            const uint32_t g1 = s1[ro];
            #pragma unroll
            for (int d = 0; d < 4; ++d) {
                const int qe = qe0 + (d & 1) * 8 + (d >> 1);
                pk[0][mt].uu[d] = ((g0 >> qe) & 1u) * 0x3F80u | ((g0 >> (qe + 4)) & 1u) * 0x3F800000u;
                pk[1][mt].uu[d] = ((g1 >> qe) & 1u) * 0x3F80u | ((g1 >> (qe + 4)) & 1u) * 0x3F800000u;
            }
        }
        #pragma unroll
        for (int nt = 0; nt < 4; ++nt) {
            const size_t fo = (size_t)(kt * 8 + Nq * 4 + nt) * 1024 + lane * 8;
            const bf16x8 bhi = *reinterpret_cast<const bf16x8*>(wf + fo);
            const bf16x8 blo = *reinterpret_cast<const bf16x8*>(wf + fo + 512);
            #pragma unroll
            for (int mt = 0; mt < 2; ++mt) {
                acc[0][mt][nt] = __builtin_amdgcn_mfma_f32_16x16x32_bf16(pk[0][mt].vv, bhi, acc[0][mt][nt], 0, 0, 0);
                acc[0][mt][nt] = __builtin_amdgcn_mfma_f32_16x16x32_bf16(pk[0][mt].vv, blo, acc[0][mt][nt], 0, 0, 0);
                acc[1][mt][nt] = __builtin_amdgcn_mfma_f32_16x16x32_bf16(pk[1][mt].vv, bhi, acc[1][mt][nt], 0, 0, 0);
                acc[1][mt][nt] = __builtin_amdgcn_mfma_f32_16x16x32_bf16(pk[1][mt].vv, blo, acc[1][mt][nt], 0, 0, 0);
            }
        }
    }

    // ---- epilogue: H transposed [b][t][100]. C/D: col=u, row=lg*4+r ----
    #pragma unroll
    for (int tt = 0; tt < 2; ++tt) {
        const int t = 2 * tp + tt;
        #pragma unroll
        for (int mt = 0; mt < 2; ++mt) {
            const int rowG = b0 + Mhalf * 32 + mt * 16 + lg * 4;
            #pragma unroll
            for (int nt = 0; nt < 4; ++nt) {
                const int col = (Nq * 4 + nt) * 16 + u;
                if (col < DH) {
                    #pragma unroll
                    for (int r = 0; r < 4; ++r)
                        __builtin_nontemporal_store(acc[tt][mt][nt][r],
                            &H[(size_t)(rowG + r) * (32 * DH) + t * DH + col]);
                }
            }
        }
    }
}

// ---------------- K2: IF scan over t + logits = cnt @ W2^T ----------------
// H transposed: row b = 3200 consecutive floats (t-major).
__global__ __launch_bounds__(256) void snn_scan(const float* __restrict__ H,
                                                const float* __restrict__ W2,
                                                float* __restrict__ out) {
    __shared__ float cbuf[2][104];
    __shared__ float w2s[1000];
    const int tid = threadIdx.x;
    const int r = tid >> 7, h = tid & 127;
    const size_t b = (size_t)blockIdx.x * 2 + r;
    for (int i = tid; i < 1000; i += 256) w2s[i] = W2[i];

    float cnt = 0.f;
    if (h < DH) {
        float hv[32];
        #pragma unroll
        for (int t = 0; t < 32; ++t) hv[t] = H[b * (32 * DH) + t * DH + h];
        float v = 0.f;
        #pragma unroll
        for (int t = 0; t < 32; ++t) {
            v += hv[t];
            float s = (v - 1.0f > 0.0f) ? 1.0f : 0.0f;  // exact reference semantics
            v -= s;
            cnt += s;
        }
    }
    if (h < DH) cbuf[r][h] = cnt;
    __syncthreads();
    if (tid < 20) {
        const int rr = tid / 10, o = tid % 10;
        float s = 0.f;
        for (int hh = 0; hh < DH; ++hh) s += cbuf[rr][hh] * w2s[o * DH + hh];
        out[((size_t)blockIdx.x * 2 + rr) * 10 + o] = s;
    }
}

extern "C" void kernel_launch(void* const* d_in, const int* in_sizes, int n_in,
                              void* d_out, int out_size, void* d_ws, size_t ws_size,
                              hipStream_t stream) {
    const float* x     = (const float*)d_in[0];   // [8192,784]
    const float* noise = (const float*)d_in[1];   // [32,8192,784]
    const float* W1    = (const float*)d_in[2];   // [100,784]
    const float* W2    = (const float*)d_in[3];   // [10,100]
    float* out = (float*)d_out;                   // [8192,10]

    unsigned short* wf = (unsigned short*)d_ws;                      // 400 KB W1 frags
    float* H = (float*)((char*)d_ws + (1u << 20));                   // 104.9 MB H (transposed)

    prep_w1<<<50, 256, 0, stream>>>(W1, wf);
    snn_gemm2<<<2048, 256, 0, stream>>>(x, noise, wf, H);
    snn_scan<<<4096, 256, 0, stream>>>(H, W2, out);
}